// Round 1
// baseline (778.008 us; speedup 1.0000x reference)
//
#include <hip/hip_runtime.h>

typedef unsigned short u16;
typedef unsigned int u32;
typedef __attribute__((ext_vector_type(4))) float f32x4;
typedef __bf16 bf16x8 __attribute__((ext_vector_type(8)));

// ---------- small helpers ----------
__device__ __forceinline__ u16 f2bf(float x) {
    u32 u = __builtin_bit_cast(u32, x);
    u += 0x7FFFu + ((u >> 16) & 1u);   // RNE
    return (u16)(u >> 16);
}
__device__ __forceinline__ float bf2f(u16 u) {
    return __builtin_bit_cast(float, ((u32)u) << 16);
}
__device__ __forceinline__ void gld_lds16(void* lds, const void* g) {
    __builtin_amdgcn_global_load_lds(
        (const __attribute__((address_space(1))) void*)g,
        (__attribute__((address_space(3))) void*)lds, 16, 0, 0);
}
__device__ __forceinline__ void merge_ms(float& m, float& s, float mo, float so) {
    float mn = fmaxf(m, mo);
    s = s * __expf(m - mn) + so * __expf(mo - mn);
    m = mn;
}
__device__ __forceinline__ void wave_reduce_ms(float& m, float& s) {
#pragma unroll
    for (int off = 32; off; off >>= 1) {
        float mo = __shfl_xor(m, off);
        float so = __shfl_xor(s, off);
        merge_ms(m, s, mo, so);
    }
}
__device__ __forceinline__ void block_reduce_ms(float& m, float& s, float* red, int tid) {
    wave_reduce_ms(m, s);
    __syncthreads();
    if ((tid & 63) == 0) { red[(tid >> 6) * 2] = m; red[(tid >> 6) * 2 + 1] = s; }
    __syncthreads();
    float M = red[0], S = red[1];
#pragma unroll
    for (int w = 1; w < 4; w++) merge_ms(M, S, red[w * 2], red[w * 2 + 1]);
    m = M; s = S;
}

// ---------- f32 -> bf16 convert (n % 4 == 0) ----------
__global__ __launch_bounds__(256) void cvt_kernel(const float* __restrict__ src,
                                                  u16* __restrict__ dst, int n) {
    int idx = blockIdx.x * blockDim.x + threadIdx.x;
    int stride = gridDim.x * blockDim.x;
    for (int i = idx * 4; i < n; i += stride * 4) {
        float4 v = *(const float4*)(src + i);
        ushort4 o;
        o.x = f2bf(v.x); o.y = f2bf(v.y); o.z = f2bf(v.z); o.w = f2bf(v.w);
        *(ushort4*)(dst + i) = o;
    }
}

// ---------- 128x128 NT bf16 GEMM (m97 structure) ----------
// C[m,n] = sum_k A[m,k]*B[n,k].  A: M x K (row stride lda), B: N x K (row stride ldb).
// BF16_OUT=1: write bf16 to Cb (stride ldc). Else f32 to C at C[r*ldc + c_off + c].
template <int BF16_OUT>
__global__ __launch_bounds__(256) void gemm_nt(const u16* __restrict__ A, int lda,
                                               const u16* __restrict__ B, int ldb,
                                               float* __restrict__ C, u16* __restrict__ Cb,
                                               long ldc, long c_off, int K) {
    __shared__ u16 lA[128 * 32];
    __shared__ u16 lB[128 * 32];
    const int tid = threadIdx.x;
    const int lane = tid & 63, wv = tid >> 6;
    const int m0 = blockIdx.y * 128, n0 = blockIdx.x * 128;

    // staging: chunk i (of 512 16B chunks) -> lds byte i*16; i = p*256 + wv*64 + lane
    const u16* gA0 = A + (size_t)(m0 + (tid >> 2)) * lda + (tid & 3) * 8;
    const u16* gB0 = B + (size_t)(n0 + (tid >> 2)) * ldb + (tid & 3) * 8;
    char* dA = (char*)lA + wv * 1024;
    char* dB = (char*)lB + wv * 1024;

    f32x4 acc[4][4] = {};
    const int wm = wv >> 1, wn = wv & 1;
    const int lr = lane & 15;
    const int lk = (lane >> 4) * 8;

    for (int kt = 0; kt < K; kt += 32) {
        __syncthreads();
        gld_lds16(dA, gA0);
        gld_lds16(dA + 4096, gA0 + 64 * (size_t)lda);
        gld_lds16(dB, gB0);
        gld_lds16(dB + 4096, gB0 + 64 * (size_t)ldb);
        gA0 += 32; gB0 += 32;
        __syncthreads();

        bf16x8 af[4], bfr[4];
#pragma unroll
        for (int i = 0; i < 4; i++) {
            af[i]  = *(const bf16x8*)(lA + (wm * 64 + i * 16 + lr) * 32 + lk);
            bfr[i] = *(const bf16x8*)(lB + (wn * 64 + i * 16 + lr) * 32 + lk);
        }
#pragma unroll
        for (int i = 0; i < 4; i++)
#pragma unroll
            for (int j = 0; j < 4; j++)
                acc[i][j] = __builtin_amdgcn_mfma_f32_16x16x32_bf16(af[i], bfr[j], acc[i][j], 0, 0, 0);
    }

    const int cr = (lane >> 4) * 4;
    const int cc = lane & 15;
#pragma unroll
    for (int i = 0; i < 4; i++) {
        int rbase = m0 + wm * 64 + i * 16 + cr;
#pragma unroll
        for (int j = 0; j < 4; j++) {
            int c = n0 + wn * 64 + j * 16 + cc;
#pragma unroll
            for (int q = 0; q < 4; q++) {
                size_t r = (size_t)(rbase + q);
                if (BF16_OUT) Cb[r * (size_t)ldc + c] = f2bf(acc[i][j][q]);
                else          C[r * (size_t)ldc + (size_t)c_off + c] = acc[i][j][q];
            }
        }
    }
}

// ---------- head softmax: in-place log_softmax over cols [0,10002), save stats ----------
// stats per row (8 f32): [0]=prior0(lp[9999]) [1]=prior1(lp[10000]) [2]=save0(lp[10000]) [3]=save1(lp[10001]) [4]=t0max [5]=t0logZ
__global__ __launch_bounds__(256) void head_softmax(float* __restrict__ out,
                                                    float* __restrict__ stats) {
    const int row = blockIdx.x, tid = threadIdx.x;
    float* p = out + (size_t)row * 50257;
    __shared__ float sm[10002];
    __shared__ float red[16];
    float m = -3.4e38f, s = 0.f;
    for (int c = tid; c < 10002; c += 256) {
        float x = p[c];
        sm[c] = x;
        float m2 = fmaxf(m, x);
        s = s * __expf(m - m2) + __expf(x - m2);
        m = m2;
    }
    block_reduce_ms(m, s, red, tid);
    float A = m + __logf(s);
    for (int c = tid; c < 10002; c += 256) p[c] = sm[c] - A;
    if (tid == 0) {
        float* st = stats + row * 8;
        st[0] = sm[9999] - A;
        st[1] = sm[10000] - A;
        st[2] = sm[10000] - A;
        st[3] = sm[10001] - A;
    }
}

// ---------- tail0 row stats over raw logits in out[:,10000:50000) (masked rows only) ----------
__global__ __launch_bounds__(256) void tail0_stats(const float* __restrict__ out,
                                                   const int* __restrict__ tgt,
                                                   float* __restrict__ stats) {
    const int row = blockIdx.x, tid = threadIdx.x;
    int t = tgt[row];
    if (t < 10000 || t >= 50000) return;
    const float* p = out + (size_t)row * 50257 + 10000;
    __shared__ float red[16];
    float m = -3.4e38f, s = 0.f;
    for (int c = tid; c < 40000; c += 256) {
        float x = p[c];
        float m2 = fmaxf(m, x);
        s = s * __expf(m - m2) + __expf(x - m2);
        m = m2;
    }
    block_reduce_ms(m, s, red, tid);
    if (tid == 0) {
        stats[row * 8 + 4] = m;
        stats[row * 8 + 5] = __logf(s);
    }
}

// ---------- tail0 normalize in place / zero-fill unmasked ----------
__global__ __launch_bounds__(256) void tail0_norm(float* __restrict__ out,
                                                  const int* __restrict__ tgt,
                                                  const float* __restrict__ stats) {
    const int row = blockIdx.x;
    const int chunk = blockIdx.y;  // 0..9, 4000 cols each
    const int tid = threadIdx.x;
    float* p = out + (size_t)row * 50257 + 10000 + chunk * 4000;
    int t = tgt[row];
    const float* st = stats + row * 8;
    if (t >= 10000 && t < 50000) {
        float A = st[4] + st[5] - st[0];  // raw - max - logZ + prior0
        for (int c = tid; c < 4000; c += 256) p[c] = p[c] - A;
    } else {
        float v0 = st[2], v1 = st[3];
        for (int c = tid; c < 4000; c += 256) {
            int gc = chunk * 4000 + c;
            float v = 0.f;
            if (gc == 0) v = v0;
            else if (gc == 1) v = v1;
            p[c] = v;
        }
    }
}

// ---------- tail1: tiny GEMM + log_softmax + masked write for cols [50000,50257) ----------
__global__ __launch_bounds__(256) void tail1_kernel(float* __restrict__ out,
                                                    const int* __restrict__ tgt,
                                                    const u16* __restrict__ proj,
                                                    const u16* __restrict__ t1b,
                                                    const float* __restrict__ stats) {
    const int row = blockIdx.x, tid = threadIdx.x;
    float* p = out + (size_t)row * 50257 + 50000;
    int t = tgt[row];
    if (t < 50000) {
        for (int c = tid; c < 257; c += 256) p[c] = 0.f;
        return;
    }
    __shared__ float pr[256];
    __shared__ float lg[257];
    __shared__ float red[16];
    pr[tid] = bf2f(proj[(size_t)row * 1280 + 1024 + tid]);
    __syncthreads();
    for (int c = tid; c < 257; c += 256) {
        const u16* w = t1b + c * 256;
        float acc = 0.f;
        for (int k = 0; k < 256; k++) acc += bf2f(w[k]) * pr[k];
        lg[c] = acc;
    }
    __syncthreads();
    float m = -3.4e38f, s = 0.f;
    for (int c = tid; c < 257; c += 256) {
        float x = lg[c];
        float m2 = fmaxf(m, x);
        s = s * __expf(m - m2) + __expf(x - m2);
        m = m2;
    }
    block_reduce_ms(m, s, red, tid);
    float A = m + __logf(s) - stats[row * 8 + 1];  // + prior1
    for (int c = tid; c < 257; c += 256) p[c] = lg[c] - A;
}

// ---------- workspace layout (bytes) ----------
#define OFF_XI    0UL            // 2048*1024*2        = 4,194,304
#define OFF_HEADW 4194304UL      // 10112*1024*2       = 20,709,376
#define OFF_TAB   24903680UL     // 1280*1024*2        = 2,621,440
#define OFF_T0B   27525120UL     // 40064*1024*2       = 82,051,072
#define OFF_T1B   109576192UL    // 257*256*2          = 131,584
#define OFF_PROJ  109707776UL    // 2048*1280*2        = 5,242,880
#define OFF_STATS 114950656UL    // 2048*8*4           = 65,536

extern "C" void kernel_launch(void* const* d_in, const int* in_sizes, int n_in,
                              void* d_out, int out_size, void* d_ws, size_t ws_size,
                              hipStream_t stream) {
    const float* x   = (const float*)d_in[0];
    const int*   tgt = (const int*)d_in[1];
    const float* hw  = (const float*)d_in[2];
    const float* t0a = (const float*)d_in[3];
    const float* t0b = (const float*)d_in[4];
    const float* t1a = (const float*)d_in[5];
    const float* t1b = (const float*)d_in[6];
    float* out = (float*)d_out;
    char* ws = (char*)d_ws;

    u16* XI   = (u16*)(ws + OFF_XI);
    u16* HW   = (u16*)(ws + OFF_HEADW);
    u16* TAB  = (u16*)(ws + OFF_TAB);
    u16* T0B  = (u16*)(ws + OFF_T0B);
    u16* T1B  = (u16*)(ws + OFF_T1B);
    u16* PROJ = (u16*)(ws + OFF_PROJ);
    float* ST = (float*)(ws + OFF_STATS);

    // 1) bf16 conversions
    cvt_kernel<<<1024, 256, 0, stream>>>(x, XI, 2048 * 1024);
    cvt_kernel<<<2048, 256, 0, stream>>>(hw, HW, 10002 * 1024);
    cvt_kernel<<<512, 256, 0, stream>>>(t0a, TAB, 1024 * 1024);
    cvt_kernel<<<256, 256, 0, stream>>>(t1a, TAB + 1024 * 1024, 256 * 1024);
    cvt_kernel<<<2048, 256, 0, stream>>>(t0b, T0B, 40000 * 1024);
    cvt_kernel<<<64, 256, 0, stream>>>(t1b, T1B, 257 * 256);
    hipMemsetAsync(HW + 10002 * 1024, 0, 110 * 1024 * 2, stream);   // pad head_w rows
    hipMemsetAsync(T0B + 40000 * 1024, 0, 64 * 1024 * 2, stream);   // pad t0b rows

    // 2) head GEMM: raw logits -> out cols [0,10112)
    gemm_nt<0><<<dim3(10112 / 128, 2048 / 128), 256, 0, stream>>>(
        XI, 1024, HW, 1024, out, (u16*)nullptr, 50257L, 0L, 1024);

    // 3) head log_softmax in place + stats (must precede tail0 GEMM clobbering cols 10000+)
    head_softmax<<<2048, 256, 0, stream>>>(out, ST);

    // 4) proj GEMM: [xi @ t0a.T | xi @ t1a.T] -> bf16 (2048 x 1280)
    gemm_nt<1><<<dim3(1280 / 128, 2048 / 128), 256, 0, stream>>>(
        XI, 1024, TAB, 1024, (float*)nullptr, PROJ, 1280L, 0L, 1024);

    // 5) tail0 GEMM: raw logits -> out cols [10000,50064)
    gemm_nt<0><<<dim3(40064 / 128, 2048 / 128), 256, 0, stream>>>(
        PROJ, 1280, T0B, 1024, out, (u16*)nullptr, 50257L, 10000L, 1024);

    // 6) tail0 stats (masked rows) + in-place normalize / zero-fill
    tail0_stats<<<2048, 256, 0, stream>>>(out, tgt, ST);
    tail0_norm<<<dim3(2048, 10), 256, 0, stream>>>(out, tgt, ST);

    // 7) tail1 (also rewrites tail0 GEMM spill cols [50000,50064))
    tail1_kernel<<<2048, 256, 0, stream>>>(out, tgt, PROJ, T1B, ST);
}

// Round 2
// 639.815 us; speedup vs baseline: 1.2160x; 1.2160x over previous
//
#include <hip/hip_runtime.h>

typedef unsigned short u16;
typedef unsigned int u32;
typedef __attribute__((ext_vector_type(4))) float f32x4;
typedef __bf16 bf16x8 __attribute__((ext_vector_type(8)));
typedef __attribute__((ext_vector_type(8))) unsigned short u16x8;

// ---------- small helpers ----------
__device__ __forceinline__ u16 f2bf(float x) {
    u32 u = __builtin_bit_cast(u32, x);
    u += 0x7FFFu + ((u >> 16) & 1u);   // RNE
    return (u16)(u >> 16);
}
__device__ __forceinline__ float bf2f(u16 u) {
    return __builtin_bit_cast(float, ((u32)u) << 16);
}
__device__ __forceinline__ void gld_lds16(void* lds, const void* g) {
    __builtin_amdgcn_global_load_lds(
        (const __attribute__((address_space(1))) void*)g,
        (__attribute__((address_space(3))) void*)lds, 16, 0, 0);
}
__device__ __forceinline__ void merge_ms(float& m, float& s, float mo, float so) {
    float mn = fmaxf(m, mo);
    s = s * __expf(m - mn) + so * __expf(mo - mn);
    m = mn;
}
__device__ __forceinline__ void wave_reduce_ms(float& m, float& s) {
#pragma unroll
    for (int off = 32; off; off >>= 1) {
        float mo = __shfl_xor(m, off);
        float so = __shfl_xor(s, off);
        merge_ms(m, s, mo, so);
    }
}
__device__ __forceinline__ void block_reduce_ms(float& m, float& s, float* red, int tid) {
    wave_reduce_ms(m, s);
    __syncthreads();
    if ((tid & 63) == 0) { red[(tid >> 6) * 2] = m; red[(tid >> 6) * 2 + 1] = s; }
    __syncthreads();
    float M = red[0], S = red[1];
#pragma unroll
    for (int w = 1; w < 4; w++) merge_ms(M, S, red[w * 2], red[w * 2 + 1]);
    m = M; s = S;
}

// bf16 pack location inside an output row (bytes, row-relative):
// region [10000,50000) f32 = bytes [40000,200000). Pack 40064 bf16 (80128B)
// at top: byte 119872 - ((row*4)&15) so the base is 16B-aligned despite the
// 201028B row stride. u16 index: row*100514 + 59936 - ((row*2)&7).
__device__ __forceinline__ size_t pack_base_u16(long row) {
    return (size_t)row * 100514 + 59936 - ((row * 2) & 7);
}

// ---------- f32 -> bf16 convert (n % 4 == 0) ----------
__global__ __launch_bounds__(256) void cvt_kernel(const float* __restrict__ src,
                                                  u16* __restrict__ dst, int n) {
    int idx = blockIdx.x * blockDim.x + threadIdx.x;
    int stride = gridDim.x * blockDim.x;
    for (int i = idx * 4; i < n; i += stride * 4) {
        float4 v = *(const float4*)(src + i);
        ushort4 o;
        o.x = f2bf(v.x); o.y = f2bf(v.y); o.z = f2bf(v.z); o.w = f2bf(v.w);
        *(ushort4*)(dst + i) = o;
    }
}

// ---------- build compact row map (1 block) ----------
// cntbuf: [0]=cnt (masked rows), [1]=cnt padded to 128, [2]=dummy (first unmasked row)
__global__ __launch_bounds__(256) void build_map(const int* __restrict__ tgt,
                                                 int* __restrict__ rowlist,
                                                 int* __restrict__ cntbuf) {
    __shared__ int cs[257];
    __shared__ int fu[256];
    int t = threadIdx.x;
    int cnt_local = 0, first_un = 1 << 30;
    int mk[8];
#pragma unroll
    for (int k = 0; k < 8; k++) {
        int r = t * 8 + k;
        int tg = tgt[r];
        int m = (tg >= 10000 && tg < 50000) ? 1 : 0;
        mk[k] = m;
        cnt_local += m;
        if (!m && first_un == (1 << 30)) first_un = r;
    }
    cs[t + 1] = cnt_local;
    fu[t] = first_un;
    __syncthreads();
    if (t == 0) {
        cs[0] = 0;
        for (int i = 1; i <= 256; i++) cs[i] += cs[i - 1];
        int d = 1 << 30;
        for (int i = 0; i < 256; i++) d = min(d, fu[i]);
        if (d == (1 << 30)) d = 0;
        int cnt = cs[256];
        cntbuf[0] = cnt;
        cntbuf[1] = (cnt + 127) & ~127;
        cntbuf[2] = d;
    }
    __syncthreads();
    int off = cs[t];
#pragma unroll
    for (int k = 0; k < 8; k++)
        if (mk[k]) rowlist[off++] = t * 8 + k;
    int cnt = cs[256], cntp = (cnt + 127) & ~127, d = cntbuf[2];
    for (int j = cnt + t; j < cntp; j += 256) rowlist[j] = d;
}

// ---------- gather masked PROJ rows (first 1024 cols) into compact A ----------
__global__ __launch_bounds__(256) void gather_proj(const u16* __restrict__ PROJ,
                                                   const int* __restrict__ rowlist,
                                                   const int* __restrict__ cntbuf,
                                                   u16* __restrict__ PROJC) {
    int r = blockIdx.x;
    if (r >= cntbuf[1]) return;
    int t = threadIdx.x;
    if (r < cntbuf[0]) {
        const u16* s = PROJ + (size_t)rowlist[r] * 1280;
        *(ushort4*)(PROJC + (size_t)r * 1024 + t * 4) = *(const ushort4*)(s + t * 4);
    } else {
        ushort4 z = {0, 0, 0, 0};
        *(ushort4*)(PROJC + (size_t)r * 1024 + t * 4) = z;
    }
}

// ---------- 128x128 NT bf16 GEMM (m97 structure), grid: x=M-blocks (fast), y=N-blocks ----------
// MODE 0: f32 direct to C[r*ldc + c_off + c]
// MODE 1: bf16 direct to Cb[r*ldc + c]
// MODE 2: bf16 scatter via rowlist into packed out-rows + per-64col exp-sum partials
template <int MODE>
__global__ __launch_bounds__(256) void gemm_nt(const u16* __restrict__ A, int lda,
                                               const u16* __restrict__ B, int ldb,
                                               float* __restrict__ C, u16* __restrict__ Cb,
                                               long ldc, long c_off, int K,
                                               const int* __restrict__ rowlist,
                                               const int* __restrict__ cntbuf,
                                               float* __restrict__ part) {
    const int m0 = blockIdx.x * 128, n0 = blockIdx.y * 128;
    if (MODE == 2) {
        if (m0 >= cntbuf[1]) return;
    }
    __shared__ u16 lA[128 * 32];
    __shared__ u16 lB[128 * 32];
    const int tid = threadIdx.x;
    const int lane = tid & 63, wv = tid >> 6;

    const u16* gA0 = A + (size_t)(m0 + (tid >> 2)) * lda + (tid & 3) * 8;
    const u16* gB0 = B + (size_t)(n0 + (tid >> 2)) * ldb + (tid & 3) * 8;
    char* dA = (char*)lA + wv * 1024;
    char* dB = (char*)lB + wv * 1024;

    f32x4 acc[4][4] = {};
    const int wm = wv >> 1, wn = wv & 1;
    const int lr = lane & 15;
    const int lk = (lane >> 4) * 8;

    for (int kt = 0; kt < K; kt += 32) {
        __syncthreads();
        gld_lds16(dA, gA0);
        gld_lds16(dA + 4096, gA0 + 64 * (size_t)lda);
        gld_lds16(dB, gB0);
        gld_lds16(dB + 4096, gB0 + 64 * (size_t)ldb);
        gA0 += 32; gB0 += 32;
        __syncthreads();

        bf16x8 af[4], bfr[4];
#pragma unroll
        for (int i = 0; i < 4; i++) {
            af[i]  = *(const bf16x8*)(lA + (wm * 64 + i * 16 + lr) * 32 + lk);
            bfr[i] = *(const bf16x8*)(lB + (wn * 64 + i * 16 + lr) * 32 + lk);
        }
#pragma unroll
        for (int i = 0; i < 4; i++)
#pragma unroll
            for (int j = 0; j < 4; j++)
                acc[i][j] = __builtin_amdgcn_mfma_f32_16x16x32_bf16(af[i], bfr[j], acc[i][j], 0, 0, 0);
    }

    const int cr = (lane >> 4) * 4;
    const int cc = lane & 15;
    if (MODE == 2) {
#pragma unroll
        for (int i = 0; i < 4; i++) {
#pragma unroll
            for (int q = 0; q < 4; q++) {
                int r = m0 + wm * 64 + i * 16 + cr + q;
                long orow = rowlist[r];
                u16* dst = Cb + pack_base_u16(orow);
                float s = 0.f;
#pragma unroll
                for (int j = 0; j < 4; j++) {
                    float v = acc[i][j][q];
                    dst[n0 + wn * 64 + j * 16 + cc] = f2bf(v);
                    s += __expf(v);
                }
                s += __shfl_xor(s, 1); s += __shfl_xor(s, 2);
                s += __shfl_xor(s, 4); s += __shfl_xor(s, 8);
                if (cc == 0) part[(size_t)r * 626 + (n0 >> 6) + wn] = s;
            }
        }
    } else {
#pragma unroll
        for (int i = 0; i < 4; i++) {
            int rbase = m0 + wm * 64 + i * 16 + cr;
#pragma unroll
            for (int j = 0; j < 4; j++) {
                int c = n0 + wn * 64 + j * 16 + cc;
#pragma unroll
                for (int q = 0; q < 4; q++) {
                    size_t r = (size_t)(rbase + q);
                    if (MODE == 1) Cb[r * (size_t)ldc + c] = f2bf(acc[i][j][q]);
                    else           C[r * (size_t)ldc + (size_t)c_off + c] = acc[i][j][q];
                }
            }
        }
    }
}

// ---------- head softmax: in-place log_softmax over cols [0,10002), save stats ----------
// stats per row (8 f32): [0]=prior0(lp[9999]) [1]=prior1(lp[10000]) [2]=save lp[10000] [3]=save lp[10001]
__global__ __launch_bounds__(256) void head_softmax(float* __restrict__ out,
                                                    float* __restrict__ stats) {
    const int row = blockIdx.x, tid = threadIdx.x;
    float* p = out + (size_t)row * 50257;
    __shared__ float sm[10002];
    __shared__ float red[16];
    float m = -3.4e38f, s = 0.f;
    for (int c = tid; c < 10002; c += 256) {
        float x = p[c];
        sm[c] = x;
        float m2 = fmaxf(m, x);
        s = s * __expf(m - m2) + __expf(x - m2);
        m = m2;
    }
    block_reduce_ms(m, s, red, tid);
    float A = m + __logf(s);
    for (int c = tid; c < 10002; c += 256) p[c] = sm[c] - A;
    if (tid == 0) {
        float* st = stats + row * 8;
        st[0] = sm[9999] - A;
        st[1] = sm[10000] - A;
        st[2] = sm[10000] - A;
        st[3] = sm[10001] - A;
    }
}

// ---------- reduce tail0 partials -> final subtract constant per masked row ----------
__global__ __launch_bounds__(256) void reduce_t0(const float* __restrict__ part,
                                                 const int* __restrict__ rowlist,
                                                 const int* __restrict__ cntbuf,
                                                 const float* __restrict__ ST,
                                                 float* __restrict__ FA) {
    int r = blockIdx.x;
    if (r >= cntbuf[0]) return;
    int tid = threadIdx.x;
    float s = 0.f;
    for (int c = tid; c < 625; c += 256) s += part[(size_t)r * 626 + c];
#pragma unroll
    for (int o = 32; o; o >>= 1) s += __shfl_xor(s, o);
    __shared__ float red[4];
    if ((tid & 63) == 0) red[tid >> 6] = s;
    __syncthreads();
    if (tid == 0) {
        float S = red[0] + red[1] + red[2] + red[3];
        int orow = rowlist[r];
        FA[orow] = __logf(S) - ST[orow * 8 + 0];   // logZ - prior0
    }
}

// ---------- tail0: in-place bf16->f32 expand+normalize (masked) / zero-fill (unmasked) ----------
__global__ __launch_bounds__(256) void tail0_norm(float* __restrict__ out,
                                                  const int* __restrict__ tgt,
                                                  const float* __restrict__ ST,
                                                  const float* __restrict__ FA) {
    const int row = blockIdx.x, tid = threadIdx.x;
    float* p = out + (size_t)row * 50257 + 10000;
    int t = tgt[row];
    if (t >= 10000 && t < 50000) {
        float A = FA[row];
        const u16* src = (const u16*)out + pack_base_u16(row);
        // chunks ascending: chunk k reads bf16 bytes [119860..+16000), writes f32
        // bytes [40000+32000k..+32000) (row-relative) — later reads never clobbered.
        for (int k = 0; k < 5; k++) {
            float v[4][8];
#pragma unroll
            for (int g = 0; g < 4; g++) {
                int o = 2048 * g + tid * 8;
                if (o < 8000) {
                    u16x8 x = *(const u16x8*)(src + 8000 * k + o);
#pragma unroll
                    for (int z = 0; z < 8; z++) v[g][z] = bf2f(x[z]);
                }
            }
            __syncthreads();
#pragma unroll
            for (int g = 0; g < 4; g++) {
                int o = 2048 * g + tid * 8;
                if (o < 8000) {
                    int e = 8000 * k + o;
#pragma unroll
                    for (int z = 0; z < 8; z++) p[e + z] = v[g][z] - A;
                }
            }
            __syncthreads();
        }
    } else {
        float v0 = ST[row * 8 + 2], v1 = ST[row * 8 + 3];
        for (int e = tid; e < 40000; e += 256) p[e] = 0.f;
        if (tid == 0) { p[0] = v0; p[1] = v1; }
    }
}

// ---------- tail1: tiny GEMM + log_softmax + masked write for cols [50000,50257) ----------
__global__ __launch_bounds__(256) void tail1_kernel(float* __restrict__ out,
                                                    const int* __restrict__ tgt,
                                                    const u16* __restrict__ proj,
                                                    const u16* __restrict__ t1b,
                                                    const float* __restrict__ stats) {
    const int row = blockIdx.x, tid = threadIdx.x;
    float* p = out + (size_t)row * 50257 + 50000;
    int t = tgt[row];
    if (t < 50000) {
        for (int c = tid; c < 257; c += 256) p[c] = 0.f;
        return;
    }
    __shared__ float pr[256];
    __shared__ float lg[257];
    __shared__ float red[16];
    pr[tid] = bf2f(proj[(size_t)row * 1280 + 1024 + tid]);
    __syncthreads();
    for (int c = tid; c < 257; c += 256) {
        const u16* w = t1b + c * 256;
        float acc = 0.f;
        for (int k = 0; k < 256; k++) acc += bf2f(w[k]) * pr[k];
        lg[c] = acc;
    }
    __syncthreads();
    float m = -3.4e38f, s = 0.f;
    for (int c = tid; c < 257; c += 256) {
        float x = lg[c];
        float m2 = fmaxf(m, x);
        s = s * __expf(m - m2) + __expf(x - m2);
        m = m2;
    }
    block_reduce_ms(m, s, red, tid);
    float A = m + __logf(s) - stats[row * 8 + 1];  // + prior1
    for (int c = tid; c < 257; c += 256) p[c] = lg[c] - A;
}

// ---------- workspace layout (bytes) ----------
#define OFF_XI    0UL            // 2048*1024*2   = 4,194,304
#define OFF_HEADW 4194304UL      // 10112*1024*2  = 20,709,376
#define OFF_TAB   24903680UL     // 1280*1024*2   = 2,621,440
#define OFF_T0B   27525120UL     // 40064*1024*2  = 82,051,072
#define OFF_T1B   109576192UL    // 257*256*2     = 131,584
#define OFF_PROJ  109707776UL    // 2048*1280*2   = 5,242,880
#define OFF_ST    114950656UL    // 2048*8*4      = 65,536
#define OFF_PROJC 115016192UL    // 2048*1024*2   = 4,194,304
#define OFF_PART  119210496UL    // 2048*626*4    = 5,128,192
#define OFF_FA    124338688UL    // 2048*4        = 8,192
#define OFF_MAP   124346880UL    // 2048*4        = 8,192
#define OFF_CNT   124355072UL    // 16

extern "C" void kernel_launch(void* const* d_in, const int* in_sizes, int n_in,
                              void* d_out, int out_size, void* d_ws, size_t ws_size,
                              hipStream_t stream) {
    const float* x   = (const float*)d_in[0];
    const int*   tgt = (const int*)d_in[1];
    const float* hw  = (const float*)d_in[2];
    const float* t0a = (const float*)d_in[3];
    const float* t0b = (const float*)d_in[4];
    const float* t1a = (const float*)d_in[5];
    const float* t1b = (const float*)d_in[6];
    float* out = (float*)d_out;
    char* ws = (char*)d_ws;

    u16* XI    = (u16*)(ws + OFF_XI);
    u16* HW    = (u16*)(ws + OFF_HEADW);
    u16* TAB   = (u16*)(ws + OFF_TAB);
    u16* T0B   = (u16*)(ws + OFF_T0B);
    u16* T1B   = (u16*)(ws + OFF_T1B);
    u16* PROJ  = (u16*)(ws + OFF_PROJ);
    float* ST  = (float*)(ws + OFF_ST);
    u16* PROJC = (u16*)(ws + OFF_PROJC);
    float* PART = (float*)(ws + OFF_PART);
    float* FA  = (float*)(ws + OFF_FA);
    int* MAP   = (int*)(ws + OFF_MAP);
    int* CNT   = (int*)(ws + OFF_CNT);

    // 1) bf16 conversions + pads
    cvt_kernel<<<1024, 256, 0, stream>>>(x, XI, 2048 * 1024);
    cvt_kernel<<<2048, 256, 0, stream>>>(hw, HW, 10002 * 1024);
    cvt_kernel<<<512, 256, 0, stream>>>(t0a, TAB, 1024 * 1024);
    cvt_kernel<<<256, 256, 0, stream>>>(t1a, TAB + 1024 * 1024, 256 * 1024);
    cvt_kernel<<<2048, 256, 0, stream>>>(t0b, T0B, 40000 * 1024);
    cvt_kernel<<<64, 256, 0, stream>>>(t1b, T1B, 257 * 256);
    hipMemsetAsync(HW + 10002 * 1024, 0, 110 * 1024 * 2, stream);
    hipMemsetAsync(T0B + 40000 * 1024, 0, 64 * 1024 * 2, stream);

    // 2) row map
    build_map<<<1, 256, 0, stream>>>(tgt, MAP, CNT);

    // 3) head GEMM (raw f32 logits -> out cols [0,10112)), M fastest for B-panel L2 reuse
    gemm_nt<0><<<dim3(16, 79), 256, 0, stream>>>(
        XI, 1024, HW, 1024, out, nullptr, 50257L, 0L, 1024, nullptr, nullptr, nullptr);

    // 4) head log_softmax in place + stats
    head_softmax<<<2048, 256, 0, stream>>>(out, ST);

    // 5) proj GEMM: [xi @ t0a.T | xi @ t1a.T] -> bf16 (2048 x 1280)
    gemm_nt<1><<<dim3(16, 10), 256, 0, stream>>>(
        XI, 1024, TAB, 1024, nullptr, PROJ, 1280L, 0L, 1024, nullptr, nullptr, nullptr);

    // 6) compact A rows
    gather_proj<<<2048, 256, 0, stream>>>(PROJ, MAP, CNT, PROJC);

    // 7) tail0 GEMM: bf16 logits packed into out rows + exp-sum partials
    gemm_nt<2><<<dim3(16, 313), 256, 0, stream>>>(
        PROJC, 1024, T0B, 1024, nullptr, (u16*)d_out, 0L, 0L, 1024, MAP, CNT, PART);

    // 8) finalize per-row constants, then expand/normalize in place
    reduce_t0<<<2048, 256, 0, stream>>>(PART, MAP, CNT, ST, FA);
    tail0_norm<<<2048, 256, 0, stream>>>(out, tgt, ST, FA);

    // 9) tail1
    tail1_kernel<<<2048, 256, 0, stream>>>(out, tgt, PROJ, T1B, ST);
}

// Round 3
// 582.158 us; speedup vs baseline: 1.3364x; 1.0990x over previous
//
#include <hip/hip_runtime.h>

typedef unsigned short u16;
typedef unsigned int u32;
typedef __attribute__((ext_vector_type(4))) float f32x4;
typedef __bf16 bf16x8 __attribute__((ext_vector_type(8)));
typedef __attribute__((ext_vector_type(8))) unsigned short u16x8;

// ---------- small helpers ----------
__device__ __forceinline__ u16 f2bf(float x) {
    u32 u = __builtin_bit_cast(u32, x);
    u += 0x7FFFu + ((u >> 16) & 1u);   // RNE
    return (u16)(u >> 16);
}
__device__ __forceinline__ float bf2f(u16 u) {
    return __builtin_bit_cast(float, ((u32)u) << 16);
}
__device__ __forceinline__ void gld_lds16(void* lds, const void* g) {
    __builtin_amdgcn_global_load_lds(
        (const __attribute__((address_space(1))) void*)g,
        (__attribute__((address_space(3))) void*)lds, 16, 0, 0);
}
__device__ __forceinline__ void merge_ms(float& m, float& s, float mo, float so) {
    float mn = fmaxf(m, mo);
    s = s * __expf(m - mn) + so * __expf(mo - mn);
    m = mn;
}
__device__ __forceinline__ void wave_reduce_ms(float& m, float& s) {
#pragma unroll
    for (int off = 32; off; off >>= 1) {
        float mo = __shfl_xor(m, off);
        float so = __shfl_xor(s, off);
        merge_ms(m, s, mo, so);
    }
}
__device__ __forceinline__ void block_reduce_ms(float& m, float& s, float* red, int tid) {
    wave_reduce_ms(m, s);
    __syncthreads();
    if ((tid & 63) == 0) { red[(tid >> 6) * 2] = m; red[(tid >> 6) * 2 + 1] = s; }
    __syncthreads();
    float M = red[0], S = red[1];
#pragma unroll
    for (int w = 1; w < 4; w++) merge_ms(M, S, red[w * 2], red[w * 2 + 1]);
    m = M; s = S;
}

// bf16 pack location inside an output row (bytes, row-relative):
// region [10000,50000) f32 = bytes [40000,200000). Pack 40192 bf16 (80384B)
// starting at byte 119872 - ((row*4)&15) so base is 16B-aligned despite the
// 201028B row stride. u16 index: row*100514 + 59936 - ((row*2)&7).
__device__ __forceinline__ size_t pack_base_u16(long row) {
    return (size_t)row * 100514 + 59936 - ((row * 2) & 7);
}

// ---------- f32 -> bf16 convert (n % 4 == 0) ----------
__global__ __launch_bounds__(256) void cvt_kernel(const float* __restrict__ src,
                                                  u16* __restrict__ dst, int n) {
    int idx = blockIdx.x * blockDim.x + threadIdx.x;
    int stride = gridDim.x * blockDim.x;
    for (int i = idx * 4; i < n; i += stride * 4) {
        float4 v = *(const float4*)(src + i);
        ushort4 o;
        o.x = f2bf(v.x); o.y = f2bf(v.y); o.z = f2bf(v.z); o.w = f2bf(v.w);
        *(ushort4*)(dst + i) = o;
    }
}

// ---------- build compact row map (1 block) ----------
// cntbuf: [0]=cnt (masked rows), [1]=cnt padded to 256, [2]=dummy (first unmasked row)
__global__ __launch_bounds__(256) void build_map(const int* __restrict__ tgt,
                                                 int* __restrict__ rowlist,
                                                 int* __restrict__ cntbuf) {
    __shared__ int cs[257];
    __shared__ int fu[256];
    int t = threadIdx.x;
    int cnt_local = 0, first_un = 1 << 30;
    int mk[8];
#pragma unroll
    for (int k = 0; k < 8; k++) {
        int r = t * 8 + k;
        int tg = tgt[r];
        int m = (tg >= 10000 && tg < 50000) ? 1 : 0;
        mk[k] = m;
        cnt_local += m;
        if (!m && first_un == (1 << 30)) first_un = r;
    }
    cs[t + 1] = cnt_local;
    fu[t] = first_un;
    __syncthreads();
    if (t == 0) {
        cs[0] = 0;
        for (int i = 1; i <= 256; i++) cs[i] += cs[i - 1];
        int d = 1 << 30;
        for (int i = 0; i < 256; i++) d = min(d, fu[i]);
        if (d == (1 << 30)) d = 0;
        int cnt = cs[256];
        cntbuf[0] = cnt;
        cntbuf[1] = (cnt + 255) & ~255;
        cntbuf[2] = d;
    }
    __syncthreads();
    int off = cs[t];
#pragma unroll
    for (int k = 0; k < 8; k++)
        if (mk[k]) rowlist[off++] = t * 8 + k;
    int cnt = cs[256], cntp = (cnt + 255) & ~255, d = cntbuf[2];
    for (int j = cnt + t; j < cntp; j += 256) rowlist[j] = d;
}

// ---------- 128x128 NT bf16 GEMM (m97 structure) for head/proj ----------
// MODE 0: f32 direct to C[r*ldc + c_off + c].  MODE 1: bf16 to Cb[r*ldc + c].
template <int MODE>
__global__ __launch_bounds__(256) void gemm_nt(const u16* __restrict__ A, int lda,
                                               const u16* __restrict__ B, int ldb,
                                               float* __restrict__ C, u16* __restrict__ Cb,
                                               long ldc, long c_off, int K) {
    __shared__ u16 lA[128 * 32];
    __shared__ u16 lB[128 * 32];
    const int tid = threadIdx.x;
    const int lane = tid & 63, wv = tid >> 6;
    const int m0 = blockIdx.x * 128, n0 = blockIdx.y * 128;

    const u16* gA0 = A + (size_t)(m0 + (tid >> 2)) * lda + (tid & 3) * 8;
    const u16* gB0 = B + (size_t)(n0 + (tid >> 2)) * ldb + (tid & 3) * 8;
    char* dA = (char*)lA + wv * 1024;
    char* dB = (char*)lB + wv * 1024;

    f32x4 acc[4][4] = {};
    const int wm = wv >> 1, wn = wv & 1;
    const int lr = lane & 15;
    const int lk = (lane >> 4) * 8;

    for (int kt = 0; kt < K; kt += 32) {
        __syncthreads();
        gld_lds16(dA, gA0);
        gld_lds16(dA + 4096, gA0 + 64 * (size_t)lda);
        gld_lds16(dB, gB0);
        gld_lds16(dB + 4096, gB0 + 64 * (size_t)ldb);
        gA0 += 32; gB0 += 32;
        __syncthreads();

        bf16x8 af[4], bfr[4];
#pragma unroll
        for (int i = 0; i < 4; i++) {
            af[i]  = *(const bf16x8*)(lA + (wm * 64 + i * 16 + lr) * 32 + lk);
            bfr[i] = *(const bf16x8*)(lB + (wn * 64 + i * 16 + lr) * 32 + lk);
        }
#pragma unroll
        for (int i = 0; i < 4; i++)
#pragma unroll
            for (int j = 0; j < 4; j++)
                acc[i][j] = __builtin_amdgcn_mfma_f32_16x16x32_bf16(af[i], bfr[j], acc[i][j], 0, 0, 0);
    }

    const int cr = (lane >> 4) * 4;
    const int cc = lane & 15;
#pragma unroll
    for (int i = 0; i < 4; i++) {
        int rbase = m0 + wm * 64 + i * 16 + cr;
#pragma unroll
        for (int j = 0; j < 4; j++) {
            int c = n0 + wn * 64 + j * 16 + cc;
#pragma unroll
            for (int q = 0; q < 4; q++) {
                size_t r = (size_t)(rbase + q);
                if (MODE == 1) Cb[r * (size_t)ldc + c] = f2bf(acc[i][j][q]);
                else           C[r * (size_t)ldc + (size_t)c_off + c] = acc[i][j][q];
            }
        }
    }
}

// ---------- 256x256 BK=64 8-wave double-buffered 2-phase GEMM (tail0) ----------
// A = PROJ rows (lda=1280) gathered via rowlist (per-lane global src for gld_lds).
// B = T0B (ldb=1024, 40192 padded rows). Epilogue: bf16 scatter into packed out
// rows + per-64col exp-sum partials.
__global__ __launch_bounds__(512, 2) void gemm256_t0(const u16* __restrict__ PROJ,
                                                     const u16* __restrict__ B,
                                                     u16* __restrict__ Cb,
                                                     const int* __restrict__ rowlist,
                                                     const int* __restrict__ cntbuf,
                                                     float* __restrict__ part) {
    const int m0 = blockIdx.x * 256, n0 = blockIdx.y * 256;
    if (m0 >= cntbuf[1]) return;
    __shared__ u16 lds[4][16384];   // [buf*2 + (0=A,1=B)][256 rows x 64 cols], 128 KiB
    const int tid = threadIdx.x;
    const int lane = tid & 63, wv = tid >> 6;
    const int wm = wv >> 2, wn = wv & 3;          // 2 x 4 wave grid, wave tile 128x64
    const int lr = lane & 15, hi = lane >> 4;

    // staging sources: chunk c = p*512 + tid covers tile-row c>>3, u16 cols (c&7)*8..+8
    const int koff = (tid & 7) * 8;
    const int rit = tid >> 3;
    const u16* srcA[4];
    const u16* srcB[4];
#pragma unroll
    for (int p = 0; p < 4; p++) {
        srcA[p] = PROJ + (size_t)rowlist[m0 + p * 64 + rit] * 1280 + koff;
        srcB[p] = B + (size_t)(n0 + p * 64 + rit) * 1024 + koff;
    }

    f32x4 acc[8][4] = {};

    auto stage = [&](int buf, int kt) {
        u16* dA = &lds[buf * 2 + 0][0] + tid * 8;
        u16* dB = &lds[buf * 2 + 1][0] + tid * 8;
#pragma unroll
        for (int p = 0; p < 4; p++) {
            gld_lds16(dA + p * 4096, srcA[p] + kt);
            gld_lds16(dB + p * 4096, srcB[p] + kt);
        }
    };
    auto compute = [&](int buf) {
        const u16* lA = &lds[buf * 2 + 0][0];
        const u16* lB = &lds[buf * 2 + 1][0];
        bf16x8 bfr[4][2];
#pragma unroll
        for (int j = 0; j < 4; j++)
#pragma unroll
            for (int ks = 0; ks < 2; ks++)
                bfr[j][ks] = *(const bf16x8*)(lB + (wn * 64 + j * 16 + lr) * 64 + ks * 32 + hi * 8);
#pragma unroll
        for (int m = 0; m < 8; m++) {
            bf16x8 a0 = *(const bf16x8*)(lA + (wm * 128 + m * 16 + lr) * 64 + hi * 8);
            bf16x8 a1 = *(const bf16x8*)(lA + (wm * 128 + m * 16 + lr) * 64 + 32 + hi * 8);
#pragma unroll
            for (int j = 0; j < 4; j++) {
                acc[m][j] = __builtin_amdgcn_mfma_f32_16x16x32_bf16(a0, bfr[j][0], acc[m][j], 0, 0, 0);
                acc[m][j] = __builtin_amdgcn_mfma_f32_16x16x32_bf16(a1, bfr[j][1], acc[m][j], 0, 0, 0);
            }
        }
    };

    // prologue
    stage(0, 0);
    __syncthreads();
    int cur = 0;
#pragma unroll 1
    for (int t = 0; t < 15; ++t) {
        stage(cur ^ 1, (t + 1) * 64);   // prefetch next K-tile (completes at barrier)
        compute(cur);
        __syncthreads();                // drains vmcnt+lgkmcnt, swaps buffers safely
        cur ^= 1;
    }
    compute(cur);

    // epilogue: bf16 scatter + exp-sum partials
    const int cr = hi * 4, cc = lr;
#pragma unroll
    for (int m = 0; m < 8; m++) {
#pragma unroll
        for (int q = 0; q < 4; q++) {
            int r = m0 + wm * 128 + m * 16 + cr + q;
            long orow = rowlist[r];
            u16* dst = Cb + pack_base_u16(orow) + n0 + wn * 64 + cc;
            float s = 0.f;
#pragma unroll
            for (int j = 0; j < 4; j++) {
                float v = acc[m][j][q];
                dst[j * 16] = f2bf(v);
                s += __expf(v);
            }
            s += __shfl_xor(s, 1); s += __shfl_xor(s, 2);
            s += __shfl_xor(s, 4); s += __shfl_xor(s, 8);
            if (cc == 0) part[(size_t)r * 628 + (n0 >> 6) + wn] = s;
        }
    }
}

// ---------- head softmax: in-place log_softmax over cols [0,10002), save stats ----------
// stats per row (8 f32): [0]=prior0(lp[9999]) [1]=prior1(lp[10000]) [2]=save lp[10000] [3]=save lp[10001]
__global__ __launch_bounds__(256) void head_softmax(float* __restrict__ out,
                                                    float* __restrict__ stats) {
    const int row = blockIdx.x, tid = threadIdx.x;
    float* p = out + (size_t)row * 50257;
    __shared__ float sm[10002];
    __shared__ float red[16];
    float m = -3.4e38f, s = 0.f;
    for (int c = tid; c < 10002; c += 256) {
        float x = p[c];
        sm[c] = x;
        float m2 = fmaxf(m, x);
        s = s * __expf(m - m2) + __expf(x - m2);
        m = m2;
    }
    block_reduce_ms(m, s, red, tid);
    float A = m + __logf(s);
    for (int c = tid; c < 10002; c += 256) p[c] = sm[c] - A;
    if (tid == 0) {
        float* st = stats + row * 8;
        st[0] = sm[9999] - A;
        st[1] = sm[10000] - A;
        st[2] = sm[10000] - A;
        st[3] = sm[10001] - A;
    }
}

// ---------- reduce tail0 partials -> final subtract constant per masked row ----------
__global__ __launch_bounds__(256) void reduce_t0(const float* __restrict__ part,
                                                 const int* __restrict__ rowlist,
                                                 const int* __restrict__ cntbuf,
                                                 const float* __restrict__ ST,
                                                 float* __restrict__ FA) {
    int r = blockIdx.x;
    if (r >= cntbuf[0]) return;
    int tid = threadIdx.x;
    float s = 0.f;
    for (int c = tid; c < 628; c += 256) s += part[(size_t)r * 628 + c];
#pragma unroll
    for (int o = 32; o; o >>= 1) s += __shfl_xor(s, o);
    __shared__ float red[4];
    if ((tid & 63) == 0) red[tid >> 6] = s;
    __syncthreads();
    if (tid == 0) {
        float S = red[0] + red[1] + red[2] + red[3];
        int orow = rowlist[r];
        FA[orow] = __logf(S) - ST[orow * 8 + 0];   // logZ - prior0
    }
}

// ---------- tail0: in-place bf16->f32 expand+normalize (masked) / zero-fill (unmasked) ----------
__global__ __launch_bounds__(256) void tail0_norm(float* __restrict__ out,
                                                  const int* __restrict__ tgt,
                                                  const float* __restrict__ ST,
                                                  const float* __restrict__ FA) {
    const int row = blockIdx.x, tid = threadIdx.x;
    float* p = out + (size_t)row * 50257 + 10000;
    int t = tgt[row];
    if (t >= 10000 && t < 50000) {
        float A = FA[row];
        const u16* src = (const u16*)out + pack_base_u16(row);
        // chunks ascending: chunk k reads bf16 (region top of row), writes f32 from
        // region bottom — reads stay ahead of writes (verified disjoint per chunk).
        for (int k = 0; k < 5; k++) {
            float v[4][8];
#pragma unroll
            for (int g = 0; g < 4; g++) {
                int o = 2048 * g + tid * 8;
                if (o < 8000) {
                    u16x8 x = *(const u16x8*)(src + 8000 * k + o);
#pragma unroll
                    for (int z = 0; z < 8; z++) v[g][z] = bf2f(x[z]);
                }
            }
            __syncthreads();
#pragma unroll
            for (int g = 0; g < 4; g++) {
                int o = 2048 * g + tid * 8;
                if (o < 8000) {
                    int e = 8000 * k + o;
#pragma unroll
                    for (int z = 0; z < 8; z++) p[e + z] = v[g][z] - A;
                }
            }
            __syncthreads();
        }
    } else {
        float v0 = ST[row * 8 + 2], v1 = ST[row * 8 + 3];
        for (int e = tid; e < 40000; e += 256) p[e] = 0.f;
        if (tid == 0) { p[0] = v0; p[1] = v1; }
    }
}

// ---------- tail1: tiny GEMM + log_softmax + masked write for cols [50000,50257) ----------
__global__ __launch_bounds__(256) void tail1_kernel(float* __restrict__ out,
                                                    const int* __restrict__ tgt,
                                                    const u16* __restrict__ proj,
                                                    const u16* __restrict__ t1b,
                                                    const float* __restrict__ stats) {
    const int row = blockIdx.x, tid = threadIdx.x;
    float* p = out + (size_t)row * 50257 + 50000;
    int t = tgt[row];
    if (t < 50000) {
        for (int c = tid; c < 257; c += 256) p[c] = 0.f;
        return;
    }
    __shared__ float pr[256];
    __shared__ float lg[257];
    __shared__ float red[16];
    pr[tid] = bf2f(proj[(size_t)row * 1280 + 1024 + tid]);
    __syncthreads();
    for (int c = tid; c < 257; c += 256) {
        const u16* w = t1b + c * 256;
        float acc = 0.f;
        for (int k = 0; k < 256; k++) acc += bf2f(w[k]) * pr[k];
        lg[c] = acc;
    }
    __syncthreads();
    float m = -3.4e38f, s = 0.f;
    for (int c = tid; c < 257; c += 256) {
        float x = lg[c];
        float m2 = fmaxf(m, x);
        s = s * __expf(m - m2) + __expf(x - m2);
        m = m2;
    }
    block_reduce_ms(m, s, red, tid);
    float A = m + __logf(s) - stats[row * 8 + 1];  // + prior1
    for (int c = tid; c < 257; c += 256) p[c] = lg[c] - A;
}

// ---------- workspace layout (bytes) ----------
#define OFF_XI    0UL              // 2048*1024*2   = 4,194,304
#define OFF_HEADW 4194304UL        // 10112*1024*2  = 20,709,376
#define OFF_TAB   24903680UL       // 1280*1024*2   = 2,621,440
#define OFF_T0B   27525120UL       // 40192*1024*2  = 82,313,216
#define OFF_T1B   109838336UL      // 257*256*2     = 131,584
#define OFF_PROJ  109969920UL      // 2048*1280*2   = 5,242,880
#define OFF_ST    115212800UL      // 2048*8*4      = 65,536
#define OFF_PART  115278336UL      // 2048*628*4    = 5,144,576
#define OFF_FA    120422912UL      // 2048*4        = 8,192
#define OFF_MAP   120431104UL      // 2048*4        = 8,192
#define OFF_CNT   120439296UL      // 64

extern "C" void kernel_launch(void* const* d_in, const int* in_sizes, int n_in,
                              void* d_out, int out_size, void* d_ws, size_t ws_size,
                              hipStream_t stream) {
    const float* x   = (const float*)d_in[0];
    const int*   tgt = (const int*)d_in[1];
    const float* hw  = (const float*)d_in[2];
    const float* t0a = (const float*)d_in[3];
    const float* t0b = (const float*)d_in[4];
    const float* t1a = (const float*)d_in[5];
    const float* t1b = (const float*)d_in[6];
    float* out = (float*)d_out;
    char* ws = (char*)d_ws;

    u16* XI    = (u16*)(ws + OFF_XI);
    u16* HW    = (u16*)(ws + OFF_HEADW);
    u16* TAB   = (u16*)(ws + OFF_TAB);
    u16* T0B   = (u16*)(ws + OFF_T0B);
    u16* T1B   = (u16*)(ws + OFF_T1B);
    u16* PROJ  = (u16*)(ws + OFF_PROJ);
    float* ST  = (float*)(ws + OFF_ST);
    float* PART = (float*)(ws + OFF_PART);
    float* FA  = (float*)(ws + OFF_FA);
    int* MAP   = (int*)(ws + OFF_MAP);
    int* CNT   = (int*)(ws + OFF_CNT);

    // 1) bf16 conversions + pads
    cvt_kernel<<<1024, 256, 0, stream>>>(x, XI, 2048 * 1024);
    cvt_kernel<<<2048, 256, 0, stream>>>(hw, HW, 10002 * 1024);
    cvt_kernel<<<512, 256, 0, stream>>>(t0a, TAB, 1024 * 1024);
    cvt_kernel<<<256, 256, 0, stream>>>(t1a, TAB + 1024 * 1024, 256 * 1024);
    cvt_kernel<<<2048, 256, 0, stream>>>(t0b, T0B, 40000 * 1024);
    cvt_kernel<<<64, 256, 0, stream>>>(t1b, T1B, 257 * 256);
    hipMemsetAsync(HW + 10002 * 1024, 0, 110 * 1024 * 2, stream);   // pad head_w rows
    hipMemsetAsync(T0B + 40000 * 1024, 0, 192 * 1024 * 2, stream);  // pad t0b rows to 40192

    // 2) row map (pad to 256)
    build_map<<<1, 256, 0, stream>>>(tgt, MAP, CNT);

    // 3) head GEMM (raw f32 logits -> out cols [0,10112)), M fastest for B-panel L2 reuse
    gemm_nt<0><<<dim3(16, 79), 256, 0, stream>>>(
        XI, 1024, HW, 1024, out, nullptr, 50257L, 0L, 1024);

    // 4) head log_softmax in place + stats
    head_softmax<<<2048, 256, 0, stream>>>(out, ST);

    // 5) proj GEMM: [xi @ t0a.T | xi @ t1a.T] -> bf16 (2048 x 1280)
    gemm_nt<1><<<dim3(16, 10), 256, 0, stream>>>(
        XI, 1024, TAB, 1024, nullptr, PROJ, 1280L, 0L, 1024);

    // 6) tail0 GEMM (256^2 2-phase): bf16 logits packed into out rows + exp partials
    //    A gathered on the fly from PROJ via rowlist (per-lane gld_lds source).
    gemm256_t0<<<dim3(8, 157), 512, 0, stream>>>(
        PROJ, T0B, (u16*)d_out, MAP, CNT, PART);

    // 7) finalize per-row constants, then expand/normalize in place
    reduce_t0<<<2048, 256, 0, stream>>>(PART, MAP, CNT, ST, FA);
    tail0_norm<<<2048, 256, 0, stream>>>(out, tgt, ST, FA);

    // 8) tail1
    tail1_kernel<<<2048, 256, 0, stream>>>(out, tgt, PROJ, T1B, ST);
}

// Round 4
// 558.143 us; speedup vs baseline: 1.3939x; 1.0430x over previous
//
#include <hip/hip_runtime.h>

typedef unsigned short u16;
typedef unsigned int u32;
typedef __attribute__((ext_vector_type(4))) float f32x4;
typedef __bf16 bf16x8 __attribute__((ext_vector_type(8)));
typedef __attribute__((ext_vector_type(8))) unsigned short u16x8;

// ---------- small helpers ----------
__device__ __forceinline__ u16 f2bf(float x) {
    u32 u = __builtin_bit_cast(u32, x);
    u += 0x7FFFu + ((u >> 16) & 1u);   // RNE
    return (u16)(u >> 16);
}
__device__ __forceinline__ float bf2f(u16 u) {
    return __builtin_bit_cast(float, ((u32)u) << 16);
}
__device__ __forceinline__ void gld_lds16(void* lds, const void* g) {
    __builtin_amdgcn_global_load_lds(
        (const __attribute__((address_space(1))) void*)g,
        (__attribute__((address_space(3))) void*)lds, 16, 0, 0);
}

// bf16 pack locations inside an output row (u16 index into d_out viewed as u16).
// Row byte stride 201028 ≡ 4 (mod 16); "- ((row*2)&7)" u16s makes base 16B-aligned.
// tail pack: 40192 bf16 at row bytes [119872-δ .. 200244-δ)
__device__ __forceinline__ size_t pack_base_tail(long row) {
    return (size_t)row * 100514 + 59936 - ((row * 2) & 7);
}
// head pack: 10240 bf16 at row bytes [40960-δ .. 61440-δ)  (clobbered later by tail0_norm, OK)
__device__ __forceinline__ size_t pack_base_head(long row) {
    return (size_t)row * 100514 + 20480 - ((row * 2) & 7);
}

// ---------- all f32->bf16 converts + zero-pads in one kernel ----------
__global__ __launch_bounds__(256) void cvt_all(const float* __restrict__ x,
                                               const float* __restrict__ hw,
                                               const float* __restrict__ t0a,
                                               const float* __restrict__ t1a,
                                               const float* __restrict__ t0b,
                                               const float* __restrict__ t1b,
                                               u16* __restrict__ XI, u16* __restrict__ HW,
                                               u16* __restrict__ TAB, u16* __restrict__ T0B,
                                               u16* __restrict__ T1B) {
    int b = blockIdx.x;
    const float* src; u16* dst; int n, b0, nb;
    if (b < 80)        { src = x;    dst = XI;            n = 2097152;  b0 = 0;    nb = 80;   }
    else if (b < 472)  { src = hw;   dst = HW;            n = 10242048; b0 = 80;   nb = 392;  }
    else if (b < 512)  { src = t0a;  dst = TAB;           n = 1048576;  b0 = 472;  nb = 40;   }
    else if (b < 522)  { src = t1a;  dst = TAB + 1048576; n = 262144;   b0 = 512;  nb = 10;   }
    else if (b < 2086) { src = t0b;  dst = T0B;           n = 40960000; b0 = 522;  nb = 1564; }
    else if (b < 2090) { src = t1b;  dst = T1B;           n = 65792;    b0 = 2086; nb = 4;    }
    else if (b < 2100) { src = 0;    dst = HW + 10242048; n = 243712;   b0 = 2090; nb = 10;   }
    else               { src = 0;    dst = T0B + 40960000; n = 196608;  b0 = 2100; nb = 8;    }
    int i0 = (b - b0) * 1024 + threadIdx.x * 4;
    int stride = nb * 1024;
    if (src) {
        for (int i = i0; i < n; i += stride) {
            float4 v = *(const float4*)(src + i);
            ushort4 o;
            o.x = f2bf(v.x); o.y = f2bf(v.y); o.z = f2bf(v.z); o.w = f2bf(v.w);
            *(ushort4*)(dst + i) = o;
        }
    } else {
        ushort4 z = {0, 0, 0, 0};
        for (int i = i0; i < n; i += stride) *(ushort4*)(dst + i) = z;
    }
}

// ---------- build compact row map (1 block) ----------
// cntbuf: [0]=cnt (masked rows), [1]=cnt padded to 256, [2]=dummy (first unmasked row)
__global__ __launch_bounds__(256) void build_map(const int* __restrict__ tgt,
                                                 int* __restrict__ rowlist,
                                                 int* __restrict__ cntbuf) {
    __shared__ int cs[257];
    __shared__ int fu[256];
    int t = threadIdx.x;
    int cnt_local = 0, first_un = 1 << 30;
    int mk[8];
#pragma unroll
    for (int k = 0; k < 8; k++) {
        int r = t * 8 + k;
        int tg = tgt[r];
        int m = (tg >= 10000 && tg < 50000) ? 1 : 0;
        mk[k] = m;
        cnt_local += m;
        if (!m && first_un == (1 << 30)) first_un = r;
    }
    cs[t + 1] = cnt_local;
    fu[t] = first_un;
    __syncthreads();
    if (t == 0) {
        cs[0] = 0;
        for (int i = 1; i <= 256; i++) cs[i] += cs[i - 1];
        int d = 1 << 30;
        for (int i = 0; i < 256; i++) d = min(d, fu[i]);
        if (d == (1 << 30)) d = 0;
        int cnt = cs[256];
        cntbuf[0] = cnt;
        cntbuf[1] = (cnt + 255) & ~255;
        cntbuf[2] = d;
    }
    __syncthreads();
    int off = cs[t];
#pragma unroll
    for (int k = 0; k < 8; k++)
        if (mk[k]) rowlist[off++] = t * 8 + k;
    int cnt = cs[256], cntp = (cnt + 255) & ~255, d = cntbuf[2];
    for (int j = cnt + t; j < cntp; j += 256) rowlist[j] = d;
}

// ---------- 256x256 BK=32 8-wave counted-vmcnt pipelined NT bf16 GEMM ----------
// TAIL=0 (head): A=XI (lda 1024, rows=global), B=HW (10240 rows), pack->head, part stride 160, cols<10002
// TAIL=1 (tail0): A=PROJ via rowlist (lda 1280), B=T0B (40192 rows), pack->tail, part stride 628, cols<40000
// LDS per buffer per operand: subtiled [rowblk16][kblk4][row16][k8] -> chunk c (16B) at byte c*16
// holds global (row = (c>>6)*16 + (c&15), k = ((c>>4)&3)*8 ..+8). Frag read for (R, k=hi*8):
// u16 offset (R>>4)*512 + hi*128 + (R&15)*8 -> 16 lanes read 256 contiguous bytes (conflict-free).
template <int TAIL>
__global__ __launch_bounds__(512, 2) void gemm256(const u16* __restrict__ A,
                                                  const u16* __restrict__ B,
                                                  u16* __restrict__ outpk,
                                                  const int* __restrict__ rowlist,
                                                  const int* __restrict__ cntbuf,
                                                  float* __restrict__ part) {
    const int m0 = blockIdx.x * 256, n0 = blockIdx.y * 256;
    if (TAIL) { if (m0 >= cntbuf[1]) return; }
    __shared__ u16 lds[4][16384];   // 4 bufs x (A 16KB + B 16KB) = 128 KiB
    const int tid = threadIdx.x;
    const int lane = tid & 63, wv = tid >> 6;
    const int wm = wv >> 2, wn = wv & 3;      // 2x4 wave grid, wave tile 128x64
    const int lr = lane & 15, hi = lane >> 4;

    const int c0 = tid, c1 = 512 + tid;
    int ga0 = m0 + ((c0 >> 6) << 4) + (c0 & 15);
    int ga1 = m0 + ((c1 >> 6) << 4) + (c1 & 15);
    const u16* sA0;
    const u16* sA1;
    if (TAIL) {
        sA0 = A + (size_t)rowlist[ga0] * 1280 + ((c0 >> 4) & 3) * 8;
        sA1 = A + (size_t)rowlist[ga1] * 1280 + ((c1 >> 4) & 3) * 8;
    } else {
        sA0 = A + (size_t)ga0 * 1024 + ((c0 >> 4) & 3) * 8;
        sA1 = A + (size_t)ga1 * 1024 + ((c1 >> 4) & 3) * 8;
    }
    const u16* sB0 = B + (size_t)(n0 + ((c0 >> 6) << 4) + (c0 & 15)) * 1024 + ((c0 >> 4) & 3) * 8;
    const u16* sB1 = B + (size_t)(n0 + ((c1 >> 6) << 4) + (c1 & 15)) * 1024 + ((c1 >> 4) & 3) * 8;

    f32x4 acc[8][4] = {};

    auto stage = [&](int buf, int kt) {
        char* d = (char*)&lds[buf][0] + tid * 16;
        gld_lds16(d,          sA0 + kt);
        gld_lds16(d + 8192,   sA1 + kt);
        gld_lds16(d + 16384,  sB0 + kt);
        gld_lds16(d + 24576,  sB1 + kt);
    };
    auto compute = [&](int buf) {
        const u16* LA = &lds[buf][0];
        const u16* LB = &lds[buf][8192];
        bf16x8 bfr[4];
#pragma unroll
        for (int j = 0; j < 4; j++)
            bfr[j] = *(const bf16x8*)(LB + (wn * 4 + j) * 512 + hi * 128 + lr * 8);
        __builtin_amdgcn_s_setprio(1);
#pragma unroll
        for (int m = 0; m < 8; m++) {
            bf16x8 af = *(const bf16x8*)(LA + (wm * 8 + m) * 512 + hi * 128 + lr * 8);
#pragma unroll
            for (int j = 0; j < 4; j++)
                acc[m][j] = __builtin_amdgcn_mfma_f32_16x16x32_bf16(af, bfr[j], acc[m][j], 0, 0, 0);
        }
        __builtin_amdgcn_s_setprio(0);
    };

    // K = 1024 = 32 tiles of BK=32. Pipeline depth 2: stage(t+2) in flight across barrier.
    stage(0, 0);
    stage(1, 32);
    asm volatile("s_waitcnt vmcnt(4)" ::: "memory");   // stage(0)'s 4 loads done
    __builtin_amdgcn_s_barrier();
#pragma unroll 1
    for (int t = 0; t < 30; ++t) {
        stage((t + 2) & 3, (t + 2) * 32);
        compute(t & 3);
        asm volatile("s_waitcnt vmcnt(4)" ::: "memory"); // tile t+1's loads done; t+2 in flight
        __builtin_amdgcn_s_barrier();
    }
    compute(2);                                          // t=30
    asm volatile("s_waitcnt vmcnt(0)" ::: "memory");     // tile 31's loads done
    __builtin_amdgcn_s_barrier();
    compute(3);                                          // t=31

    // epilogue: bf16 pack scatter + per-64col exp-sum partials
    const int cr = hi * 4, cc = lr;
    const int climit = TAIL ? 40000 : 10002;
    const int pstride = TAIL ? 628 : 160;
#pragma unroll
    for (int m = 0; m < 8; m++) {
#pragma unroll
        for (int q = 0; q < 4; q++) {
            int r = m0 + wm * 128 + m * 16 + cr + q;
            long orow = TAIL ? rowlist[r] : r;
            size_t base = TAIL ? pack_base_tail(orow) : pack_base_head(orow);
            u16* dst = outpk + base + n0 + wn * 64 + cc;
            float s = 0.f;
#pragma unroll
            for (int j = 0; j < 4; j++) {
                float v = acc[m][j][q];
                dst[j * 16] = f2bf(v);
                int col = n0 + wn * 64 + j * 16 + cc;
                s += (col < climit) ? __expf(v) : 0.f;
            }
            s += __shfl_xor(s, 1); s += __shfl_xor(s, 2);
            s += __shfl_xor(s, 4); s += __shfl_xor(s, 8);
            if (cc == 0) part[(size_t)r * pstride + (n0 >> 6) + wn] = s;
        }
    }
}

// ---------- 128x128 NT bf16 GEMM (m97 structure) for proj ----------
__global__ __launch_bounds__(256) void gemm_nt_bf16(const u16* __restrict__ A, int lda,
                                                    const u16* __restrict__ B, int ldb,
                                                    u16* __restrict__ Cb, long ldc, int K) {
    __shared__ u16 lA[128 * 32];
    __shared__ u16 lB[128 * 32];
    const int tid = threadIdx.x;
    const int lane = tid & 63, wv = tid >> 6;
    const int m0 = blockIdx.x * 128, n0 = blockIdx.y * 128;

    const u16* gA0 = A + (size_t)(m0 + (tid >> 2)) * lda + (tid & 3) * 8;
    const u16* gB0 = B + (size_t)(n0 + (tid >> 2)) * ldb + (tid & 3) * 8;
    char* dA = (char*)lA + wv * 1024;
    char* dB = (char*)lB + wv * 1024;

    f32x4 acc[4][4] = {};
    const int wm = wv >> 1, wn = wv & 1;
    const int lr = lane & 15;
    const int lk = (lane >> 4) * 8;

    for (int kt = 0; kt < K; kt += 32) {
        __syncthreads();
        gld_lds16(dA, gA0);
        gld_lds16(dA + 4096, gA0 + 64 * (size_t)lda);
        gld_lds16(dB, gB0);
        gld_lds16(dB + 4096, gB0 + 64 * (size_t)ldb);
        gA0 += 32; gB0 += 32;
        __syncthreads();

        bf16x8 af[4], bfr[4];
#pragma unroll
        for (int i = 0; i < 4; i++) {
            af[i]  = *(const bf16x8*)(lA + (wm * 64 + i * 16 + lr) * 32 + lk);
            bfr[i] = *(const bf16x8*)(lB + (wn * 64 + i * 16 + lr) * 32 + lk);
        }
#pragma unroll
        for (int i = 0; i < 4; i++)
#pragma unroll
            for (int j = 0; j < 4; j++)
                acc[i][j] = __builtin_amdgcn_mfma_f32_16x16x32_bf16(af[i], bfr[j], acc[i][j], 0, 0, 0);
    }

    const int cr = (lane >> 4) * 4;
    const int cc = lane & 15;
#pragma unroll
    for (int i = 0; i < 4; i++) {
        int rbase = m0 + wm * 64 + i * 16 + cr;
#pragma unroll
        for (int j = 0; j < 4; j++) {
            int c = n0 + wn * 64 + j * 16 + cc;
#pragma unroll
            for (int q = 0; q < 4; q++)
                Cb[(size_t)(rbase + q) * (size_t)ldc + c] = f2bf(acc[i][j][q]);
        }
    }
}

// ---------- head: reduce partials -> logZ; expand bf16 pack -> f32 lp; save stats ----------
// stats per row (8 f32): [0]=prior0(lp[9999]) [1]=prior1(lp[10000]) [2]=lp[10000] [3]=lp[10001]
__global__ __launch_bounds__(256) void head_norm(float* __restrict__ out,
                                                 float* __restrict__ stats,
                                                 const float* __restrict__ parth) {
    const int row = blockIdx.x, tid = threadIdx.x;
    float s = (tid < 160) ? parth[(size_t)row * 160 + tid] : 0.f;
#pragma unroll
    for (int o = 32; o; o >>= 1) s += __shfl_xor(s, o);
    __shared__ float red[4];
    if ((tid & 63) == 0) red[tid >> 6] = s;
    __syncthreads();
    float logZ = __logf(red[0] + red[1] + red[2] + red[3]);
    const u16* pk = (const u16*)out + pack_base_head(row);
    float* p = out + (size_t)row * 50257;
    // reads: row bytes [40944..61440); writes: [0,40008) — disjoint, no ordering needed
    for (int k = 0; k < 5; k++) {
        int c0 = k * 2048 + tid * 8;
        if (c0 + 8 <= 10002) {
            u16x8 xv = *(const u16x8*)(pk + c0);
#pragma unroll
            for (int z = 0; z < 8; z++) p[c0 + z] = bf2f(xv[z]) - logZ;
        } else if (c0 < 10002) {
            for (int z = 0; c0 + z < 10002; z++) p[c0 + z] = bf2f(pk[c0 + z]) - logZ;
        }
    }
    if (tid == 0) {
        float* st = stats + row * 8;
        float l0 = bf2f(pk[9999]) - logZ;
        float l1 = bf2f(pk[10000]) - logZ;
        float l2 = bf2f(pk[10001]) - logZ;
        st[0] = l0; st[1] = l1; st[2] = l1; st[3] = l2;
    }
}

// ---------- reduce tail0 partials -> final subtract constant per masked row ----------
__global__ __launch_bounds__(256) void reduce_t0(const float* __restrict__ part,
                                                 const int* __restrict__ rowlist,
                                                 const int* __restrict__ cntbuf,
                                                 const float* __restrict__ ST,
                                                 float* __restrict__ FA) {
    int r = blockIdx.x;
    if (r >= cntbuf[0]) return;
    int tid = threadIdx.x;
    float s = 0.f;
    for (int c = tid; c < 628; c += 256) s += part[(size_t)r * 628 + c];
#pragma unroll
    for (int o = 32; o; o >>= 1) s += __shfl_xor(s, o);
    __shared__ float red[4];
    if ((tid & 63) == 0) red[tid >> 6] = s;
    __syncthreads();
    if (tid == 0) {
        float S = red[0] + red[1] + red[2] + red[3];
        int orow = rowlist[r];
        FA[orow] = __logf(S) - ST[orow * 8 + 0];   // logZ - prior0
    }
}

// ---------- tail0: in-place bf16->f32 expand+normalize (masked) / zero-fill (unmasked) ----------
__global__ __launch_bounds__(256) void tail0_norm(float* __restrict__ out,
                                                  const int* __restrict__ tgt,
                                                  const float* __restrict__ ST,
                                                  const float* __restrict__ FA) {
    const int row = blockIdx.x, tid = threadIdx.x;
    float* p = out + (size_t)row * 50257 + 10000;
    int t = tgt[row];
    if (t >= 10000 && t < 50000) {
        float A = FA[row];
        const u16* src = (const u16*)out + pack_base_tail(row);
        // chunk k: all reads (into regs) precede all writes (syncthreads between);
        // cross-chunk read/write ranges verified disjoint.
        for (int k = 0; k < 5; k++) {
            float v[4][8];
#pragma unroll
            for (int g = 0; g < 4; g++) {
                int o = 2048 * g + tid * 8;
                if (o < 8000) {
                    u16x8 xv = *(const u16x8*)(src + 8000 * k + o);
#pragma unroll
                    for (int z = 0; z < 8; z++) v[g][z] = bf2f(xv[z]);
                }
            }
            __syncthreads();
#pragma unroll
            for (int g = 0; g < 4; g++) {
                int o = 2048 * g + tid * 8;
                if (o < 8000) {
                    int e = 8000 * k + o;
#pragma unroll
                    for (int z = 0; z < 8; z++) p[e + z] = v[g][z] - A;
                }
            }
            __syncthreads();
        }
    } else {
        float v0 = ST[row * 8 + 2], v1 = ST[row * 8 + 3];
        for (int e = tid; e < 40000; e += 256) p[e] = 0.f;
        if (tid == 0) { p[0] = v0; p[1] = v1; }
    }
}

// ---------- tail1: tiny GEMM + log_softmax + masked write for cols [50000,50257) ----------
__global__ __launch_bounds__(256) void tail1_kernel(float* __restrict__ out,
                                                    const int* __restrict__ tgt,
                                                    const u16* __restrict__ proj,
                                                    const u16* __restrict__ t1b,
                                                    const float* __restrict__ stats) {
    const int row = blockIdx.x, tid = threadIdx.x;
    float* p = out + (size_t)row * 50257 + 50000;
    int t = tgt[row];
    if (t < 50000) {
        for (int c = tid; c < 257; c += 256) p[c] = 0.f;
        return;
    }
    __shared__ float pr[256];
    __shared__ float lg[257];
    __shared__ float red[4];
    pr[tid] = bf2f(proj[(size_t)row * 1280 + 1024 + tid]);
    __syncthreads();
    for (int c = tid; c < 257; c += 256) {
        const u16* w = t1b + c * 256;
        float acc = 0.f;
        for (int k = 0; k < 256; k++) acc += bf2f(w[k]) * pr[k];
        lg[c] = acc;
    }
    __syncthreads();
    float s = 0.f;
    for (int c = tid; c < 257; c += 256) s += __expf(lg[c]);
#pragma unroll
    for (int o = 32; o; o >>= 1) s += __shfl_xor(s, o);
    if ((tid & 63) == 0) red[tid >> 6] = s;
    __syncthreads();
    float A = __logf(red[0] + red[1] + red[2] + red[3]) - stats[row * 8 + 1];  // logZ - prior1
    for (int c = tid; c < 257; c += 256) p[c] = lg[c] - A;
}

// ---------- workspace layout (bytes) ----------
#define OFF_XI    0UL              // 2048*1024*2    = 4,194,304
#define OFF_HEADW 4194304UL        // 10240*1024*2   = 20,971,520
#define OFF_TAB   25165824UL       // 1280*1024*2    = 2,621,440
#define OFF_T0B   27787264UL       // 40192*1024*2   = 82,313,216
#define OFF_T1B   110100480UL      // 257*256*2      = 131,584
#define OFF_PROJ  110232064UL      // 2048*1280*2    = 5,242,880
#define OFF_ST    115474944UL      // 2048*8*4       = 65,536
#define OFF_PART  115540480UL      // 2048*628*4     = 5,144,576
#define OFF_PARTH 120685056UL      // 2048*160*4     = 1,310,720
#define OFF_FA    121995776UL      // 2048*4
#define OFF_MAP   122003968UL      // 2048*4
#define OFF_CNT   122012160UL      // 64

extern "C" void kernel_launch(void* const* d_in, const int* in_sizes, int n_in,
                              void* d_out, int out_size, void* d_ws, size_t ws_size,
                              hipStream_t stream) {
    const float* x   = (const float*)d_in[0];
    const int*   tgt = (const int*)d_in[1];
    const float* hw  = (const float*)d_in[2];
    const float* t0a = (const float*)d_in[3];
    const float* t0b = (const float*)d_in[4];
    const float* t1a = (const float*)d_in[5];
    const float* t1b = (const float*)d_in[6];
    float* out = (float*)d_out;
    char* ws = (char*)d_ws;

    u16* XI     = (u16*)(ws + OFF_XI);
    u16* HW     = (u16*)(ws + OFF_HEADW);
    u16* TAB    = (u16*)(ws + OFF_TAB);
    u16* T0B    = (u16*)(ws + OFF_T0B);
    u16* T1B    = (u16*)(ws + OFF_T1B);
    u16* PROJ   = (u16*)(ws + OFF_PROJ);
    float* ST   = (float*)(ws + OFF_ST);
    float* PART = (float*)(ws + OFF_PART);
    float* PARTH = (float*)(ws + OFF_PARTH);
    float* FA   = (float*)(ws + OFF_FA);
    int* MAP    = (int*)(ws + OFF_MAP);
    int* CNT    = (int*)(ws + OFF_CNT);

    // 1) all converts + pads (one kernel)
    cvt_all<<<2108, 256, 0, stream>>>(x, hw, t0a, t1a, t0b, t1b, XI, HW, TAB, T0B, T1B);

    // 2) row map (padded to 256)
    build_map<<<1, 256, 0, stream>>>(tgt, MAP, CNT);

    // 3) head GEMM (256^2 pipelined): bf16 pack into out rows + exp partials
    gemm256<0><<<dim3(8, 40), 512, 0, stream>>>(XI, HW, (u16*)d_out, nullptr, nullptr, PARTH);

    // 4) head: logZ + expand to f32 lp + stats
    head_norm<<<2048, 256, 0, stream>>>(out, ST, PARTH);

    // 5) proj GEMM: [xi @ t0a.T | xi @ t1a.T] -> bf16 (2048 x 1280)
    gemm_nt_bf16<<<dim3(16, 10), 256, 0, stream>>>(XI, 1024, TAB, 1024, PROJ, 1280L, 1024);

    // 6) tail0 GEMM (256^2 pipelined, rowlist-gathered A): bf16 pack + exp partials
    gemm256<1><<<dim3(8, 157), 512, 0, stream>>>(PROJ, T0B, (u16*)d_out, MAP, CNT, PART);

    // 7) per-row constants, then expand/normalize in place
    reduce_t0<<<2048, 256, 0, stream>>>(PART, MAP, CNT, ST, FA);
    tail0_norm<<<2048, 256, 0, stream>>>(out, tgt, ST, FA);

    // 8) tail1
    tail1_kernel<<<2048, 256, 0, stream>>>(out, tgt, PROJ, T1B, ST);
}